// Round 2
// baseline (1264.681 us; speedup 1.0000x reference)
//
#include <hip/hip_runtime.h>
#include <math.h>

#define BB   4
#define NN   8192
#define BN   (BB*NN)       // 32768 points per cloud-set
#define KNN  10
#define TILE 256

#define SEPS    5.9604645e-8f        // slamch('E') = 2^-24
#define SEPS2   (SEPS*SEPS)
#define SSAFMIN 1.1754944e-38f

// ---------------------------------------------------------------------------
// Kernel A: build P[2][B][N][3]:  cloud0 = gt, cloud1 = pred[idx12]
// Auto-detect whether idx12 buffer is int32 or int64 (reference uses int64).
// ---------------------------------------------------------------------------
__global__ __launch_bounds__(256) void prep_kernel(
    const float* __restrict__ gt, const float* __restrict__ pred,
    const unsigned* __restrict__ idxw, float* __restrict__ P)
{
    __shared__ int s_is32;
    int tid = threadIdx.x;
    if (tid == 0) s_is32 = 0;
    __syncthreads();
    if (idxw[2*tid + 1] != 0u) s_is32 = 1;   // int64 => all high words 0
    __syncthreads();
    bool is64 = (s_is32 == 0);

    int point = blockIdx.x * 256 + tid;        // 0 .. 2*BN-1
    int cloud = point >> 15;                   // BN = 2^15
    int r = point & (BN - 1);
    if (cloud == 0) {
        P[(size_t)r*3+0] = gt[(size_t)r*3+0];
        P[(size_t)r*3+1] = gt[(size_t)r*3+1];
        P[(size_t)r*3+2] = gt[(size_t)r*3+2];
    } else {
        int b = r >> 13;                       // NN = 2^13
        unsigned idx = is64 ? idxw[2*(size_t)r] : idxw[r];
        const float* src = pred + ((size_t)b*NN + idx)*3;
        float* dst = P + ((size_t)(BN + r))*3;
        dst[0] = src[0]; dst[1] = src[1]; dst[2] = src[2];
    }
}

// ---------------------------------------------------------------------------
// LAPACK ssyevd 3x3 path: ssytrd('L') + sorgtr + ssteqr('V'). Sign-faithful.
// ---------------------------------------------------------------------------
__device__ __forceinline__ float f_sign(float a, float b) {
    return copysignf(a, b);                    // gfortran SIGN: sign-bit based
}
__device__ __forceinline__ float slapy2(float x, float y) {
#pragma clang fp contract(off)
    float xa = fabsf(x), ya = fabsf(y);
    float w = fmaxf(xa, ya), z = fminf(xa, ya);
    if (z == 0.0f) return w;
    float t = z / w;
    return w * __fsqrt_rn(1.0f + t*t);
}
// LAPACK >=3.10 slartg (c >= 0 convention), fast path (moderate values)
__device__ __forceinline__ void slartg_(float f, float g, float* cs, float* sn, float* r) {
#pragma clang fp contract(off)
    if (g == 0.0f)      { *cs = 1.0f; *sn = 0.0f; *r = f; }
    else if (f == 0.0f) { *cs = 0.0f; *sn = f_sign(1.0f, g); *r = fabsf(g); }
    else {
        float f1 = fabsf(f);
        float d = __fsqrt_rn(f*f + g*g);
        float p = 1.0f / d;
        *cs = f1 * p;
        *sn = g * f_sign(p, f);
        *r  = f_sign(d, f);
    }
}
__device__ void slaev2_(float a, float b, float c,
                        float* rt1, float* rt2, float* cs1, float* sn1) {
#pragma clang fp contract(off)
    float sm = a + c, df = a - c;
    float adf = fabsf(df);
    float tb = b + b;
    float ab = fabsf(tb);
    float acmx, acmn;
    if (fabsf(a) > fabsf(c)) { acmx = a; acmn = c; } else { acmx = c; acmn = a; }
    float rt;
    if (adf > ab)      { float t = ab/adf; rt = adf*__fsqrt_rn(1.0f + t*t); }
    else if (adf < ab) { float t = adf/ab; rt = ab*__fsqrt_rn(1.0f + t*t); }
    else               { rt = ab*__fsqrt_rn(2.0f); }
    int sgn1;
    if (sm < 0.0f)      { *rt1 = 0.5f*(sm - rt); sgn1 = -1;
                          *rt2 = (acmx / *rt1)*acmn - (b / *rt1)*b; }
    else if (sm > 0.0f) { *rt1 = 0.5f*(sm + rt); sgn1 = 1;
                          *rt2 = (acmx / *rt1)*acmn - (b / *rt1)*b; }
    else                { *rt1 = 0.5f*rt; *rt2 = -0.5f*rt; sgn1 = 1; }
    float cs; int sgn2;
    if (df >= 0.0f) { cs = df + rt; sgn2 = 1; } else { cs = df - rt; sgn2 = -1; }
    float acs = fabsf(cs);
    float c1, s1;
    if (acs > ab) { float ct = -tb/cs; s1 = 1.0f/__fsqrt_rn(1.0f + ct*ct); c1 = ct*s1; }
    else {
        if (ab == 0.0f) { c1 = 1.0f; s1 = 0.0f; }
        else { float tn = -cs/tb; c1 = 1.0f/__fsqrt_rn(1.0f + tn*tn); s1 = tn*c1; }
    }
    if (sgn1 == sgn2) { float tn = c1; c1 = -s1; s1 = tn; }
    *cs1 = c1; *sn1 = s1;
}

// Returns the eigenvector (column 0 after ascending sort) of the symmetric
// 3x3 [[c00,c01,c02],[c01,c11,c12],[c02,c12,c22]] per LAPACK ssyevd.
__device__ void eigh3_smallest(float c00, float c01, float c02,
                               float c11, float c12, float c22, float nv[3])
{
#pragma clang fp contract(off)
    // ---- ssytrd('L') ----
    float d[4], e[3], z[4][4];
    float tau1, v2 = 0.0f;
    float e1, d2, d3, e2;
    float alpha = c01, x = c02;
    if (x == 0.0f) {
        tau1 = 0.0f; e1 = alpha;
        d2 = c11; d3 = c22; e2 = c12;
    } else {
        float beta = -f_sign(slapy2(alpha, fabsf(x)), alpha);
        tau1 = (beta - alpha) / beta;
        v2 = x / (alpha - beta);
        e1 = beta;
        // w = tau*A22*v; w -= 0.5*tau*(w.v)*v; A22 -= v w' + w v'
        float w1 = tau1*(c11 + c12*v2);
        float w2 = tau1*(c12 + c22*v2);
        float al = -0.5f*tau1*(w1 + w2*v2);
        w1 = w1 + al;
        w2 = w2 + al*v2;
        d2 = (c11 - w1) - w1;
        e2 = (c12 - v2*w1) - w2;
        d3 = (c22 - v2*w2) - w2*v2;
    }
    d[1] = c00; d[2] = d2; d[3] = d3;
    e[1] = e1;  e[2] = e2;
    // ---- sorgtr('L'): Z = H1 ----
    z[1][1] = 1.0f; z[1][2] = 0.0f; z[1][3] = 0.0f;
    z[2][1] = 0.0f; z[3][1] = 0.0f;
    z[2][2] = 1.0f - tau1;
    float mtv = -tau1*v2;
    z[2][3] = mtv; z[3][2] = mtv;
    z[3][3] = 1.0f + mtv*v2;

    // ---- ssteqr('V', 3) ----
    const int n = 3, nm1 = 2;
    int l1 = 1, jtot = 0;
    const int nmaxit = 90;
    float cw[3], sw[3];
    int guard = 0;
    while (guard++ < 64) {
        if (l1 > n) break;
        if (l1 > 1) e[l1-1] = 0.0f;
        int m = n;
        if (l1 <= nm1) {
            for (int mi = l1; mi <= nm1; ++mi) {
                float tst = fabsf(e[mi]);
                if (tst == 0.0f) { m = mi; break; }
                if (tst <= (__fsqrt_rn(fabsf(d[mi]))*__fsqrt_rn(fabsf(d[mi+1])))*SEPS) {
                    e[mi] = 0.0f; m = mi; break;
                }
            }
        }
        int l = m >= l1 ? l1 : l1;   // l = l1
        l = l1;
        int lsv = l, lend = m, lendsv = lend;
        l1 = m + 1;
        if (lend == l) continue;
        if (fabsf(d[lend]) < fabsf(d[l])) { lend = lsv; l = lendsv; }

        if (lend > l) {
            // ---------------- QL ----------------
            while (true) {
                int m_ = lend;
                if (l != lend) {
                    for (int mi = l; mi <= lend-1; ++mi) {
                        float em = e[mi];
                        float tst = em*em;
                        if (tst <= (SEPS2*fabsf(d[mi]))*fabsf(d[mi+1]) + SSAFMIN) { m_ = mi; break; }
                    }
                }
                if (m_ < lend) e[m_] = 0.0f;
                float p = d[l];
                if (m_ == l) {                    // eigenvalue found
                    d[l] = p; l = l + 1;
                    if (l <= lend) continue; else break;
                }
                if (m_ == l + 1) {                // 2x2 -> slaev2
                    float rt1, rt2, cc, ss;
                    slaev2_(d[l], e[l], d[l+1], &rt1, &rt2, &cc, &ss);
                    for (int i = 1; i <= 3; ++i) {
                        float tmp = z[i][l+1];
                        z[i][l+1] = cc*tmp - ss*z[i][l];
                        z[i][l]   = ss*tmp + cc*z[i][l];
                    }
                    d[l] = rt1; d[l+1] = rt2; e[l] = 0.0f;
                    l = l + 2;
                    if (l <= lend) continue; else break;
                }
                if (jtot == nmaxit) break;
                jtot++;
                float g = (d[l+1] - p) / (2.0f*e[l]);
                float r = slapy2(g, 1.0f);
                g = d[m_] - p + (e[l] / (g + f_sign(r, g)));
                float s = 1.0f, c = 1.0f;
                p = 0.0f;
                for (int i = m_-1; i >= l; --i) {
                    float f = s*e[i];
                    float b = c*e[i];
                    slartg_(g, f, &c, &s, &r);
                    if (i != m_-1) e[i+1] = r;
                    g = d[i+1] - p;
                    r = (d[i] - g)*s + (2.0f*c)*b;
                    p = s*r;
                    d[i+1] = g + p;
                    g = c*r - b;
                    cw[i] = c; sw[i] = -s;
                }
                for (int j = m_-1; j >= l; --j) {   // slasr 'B'
                    float cc = cw[j], ss = sw[j];
                    for (int i = 1; i <= 3; ++i) {
                        float tmp = z[i][j+1];
                        z[i][j+1] = cc*tmp - ss*z[i][j];
                        z[i][j]   = ss*tmp + cc*z[i][j];
                    }
                }
                d[l] = d[l] - p;
                e[l] = g;
            }
        } else {
            // ---------------- QR ----------------
            while (true) {
                int m_ = lend;
                if (l != lend) {
                    for (int mi = l; mi >= lend+1; --mi) {
                        float em = e[mi-1];
                        float tst = em*em;
                        if (tst <= (SEPS2*fabsf(d[mi]))*fabsf(d[mi-1]) + SSAFMIN) { m_ = mi; break; }
                    }
                }
                if (m_ > lend) e[m_-1] = 0.0f;
                float p = d[l];
                if (m_ == l) {
                    d[l] = p; l = l - 1;
                    if (l >= lend) continue; else break;
                }
                if (m_ == l - 1) {
                    float rt1, rt2, cc, ss;
                    slaev2_(d[l-1], e[l-1], d[l], &rt1, &rt2, &cc, &ss);
                    for (int i = 1; i <= 3; ++i) {     // slasr 'F', cols (l-1,l)
                        float tmp = z[i][l];
                        z[i][l]   = cc*tmp - ss*z[i][l-1];
                        z[i][l-1] = ss*tmp + cc*z[i][l-1];
                    }
                    d[l-1] = rt1; d[l] = rt2; e[l-1] = 0.0f;
                    l = l - 2;
                    if (l >= lend) continue; else break;
                }
                if (jtot == nmaxit) break;
                jtot++;
                float g = (d[l-1] - p) / (2.0f*e[l-1]);
                float r = slapy2(g, 1.0f);
                g = d[m_] - p + (e[l-1] / (g + f_sign(r, g)));
                float s = 1.0f, c = 1.0f;
                p = 0.0f;
                for (int i = m_; i <= l-1; ++i) {
                    float f = s*e[i];
                    float b = c*e[i];
                    slartg_(g, f, &c, &s, &r);
                    if (i != m_) e[i-1] = r;
                    g = d[i] - p;
                    r = (d[i+1] - g)*s + (2.0f*c)*b;
                    p = s*r;
                    d[i] = g + p;
                    g = c*r - b;
                    cw[i] = c; sw[i] = s;
                }
                for (int j = m_; j <= l-1; ++j) {    // slasr 'F'
                    float cc = cw[j], ss = sw[j];
                    for (int i = 1; i <= 3; ++i) {
                        float tmp = z[i][j+1];
                        z[i][j+1] = cc*tmp - ss*z[i][j];
                        z[i][j]   = ss*tmp + cc*z[i][j];
                    }
                }
                d[l] = d[l] - p;
                e[l-1] = g;
            }
        }
    }
    // selection sort ascending (strict <), swap eigenvector columns
    for (int ii = 2; ii <= 3; ++ii) {
        int i = ii - 1, k = i;
        float p = d[i];
        for (int j = ii; j <= 3; ++j) if (d[j] < p) { k = j; p = d[j]; }
        if (k != i) {
            d[k] = d[i]; d[i] = p;
            for (int r2 = 1; r2 <= 3; ++r2) {
                float t = z[r2][i]; z[r2][i] = z[r2][k]; z[r2][k] = t;
            }
        }
    }
    nv[0] = z[1][1]; nv[1] = z[2][1]; nv[2] = z[3][1];
}

// ---------------------------------------------------------------------------
// Stable top-k insert: lexicographically-smallest (d, idx) pairs = top_k ties.
// Candidates arrive in increasing idx, so skipping d==worst is tie-correct.
// ---------------------------------------------------------------------------
__device__ __forceinline__ void tk_insert(float (&bd)[KNN], int (&bi)[KNN],
                                          float d, int j)
{
    float cd = d; int ci = j;
    #pragma unroll
    for (int s = 0; s < KNN; ++s) {
        float od = bd[s]; int oi = bi[s];
        bool sw = (od > cd) || ((od == cd) && (oi > ci));
        bd[s] = sw ? cd : od;
        bi[s] = sw ? ci : oi;
        cd    = sw ? od : cd;
        ci    = sw ? oi : ci;
    }
}

#define PROC(cx,cy,cz,gj) do { \
    float dx = qx-(cx), dy = qy-(cy), dz = qz-(cz); \
    float d = fmaf(dz,dz,fmaf(dy,dy,dx*dx)); \
    if (d < worst) { tk_insert(bd,bi,d,(gj)); worst = bd[KNN-1]; } \
} while (0)

// ---------------------------------------------------------------------------
// Kernel B: exact 10-NN (LDS tiles) + covariance + LAPACK-faithful eigh.
// ---------------------------------------------------------------------------
__global__ __launch_bounds__(256) void knn_normal_kernel(
    const float* __restrict__ P, float* __restrict__ Nrm)
{
    __shared__ __align__(16) float sh[TILE*3];
    int tid = threadIdx.x;
    int blk = blockIdx.x;                      // 0..255
    int pair = blk >> 5;                       // cloud*4 + batch
    int chunk = blk & 31;
    const float* __restrict__ cl = P + (size_t)pair * NN * 3;
    int q = chunk * 256 + tid;
    float qx = cl[(size_t)q*3+0];
    float qy = cl[(size_t)q*3+1];
    float qz = cl[(size_t)q*3+2];

    float bd[KNN]; int bi[KNN];
    #pragma unroll
    for (int s = 0; s < KNN; ++s) { bd[s] = 3.4e38f; bi[s] = 0x7fffffff; }
    float worst = 3.4e38f;

    for (int t = 0; t < NN/TILE; ++t) {
        __syncthreads();
        #pragma unroll
        for (int u = 0; u < 3; ++u)
            sh[u*256 + tid] = cl[(size_t)t*TILE*3 + u*256 + tid];
        __syncthreads();
        int base = t * TILE;
        for (int jq = 0; jq < TILE/4; ++jq) {
            float4 f0 = *reinterpret_cast<const float4*>(sh + 12*jq);
            float4 f1 = *reinterpret_cast<const float4*>(sh + 12*jq + 4);
            float4 f2 = *reinterpret_cast<const float4*>(sh + 12*jq + 8);
            int gb = base + 4*jq;
            PROC(f0.x, f0.y, f0.z, gb+0);
            PROC(f0.w, f1.x, f1.y, gb+1);
            PROC(f1.z, f1.w, f2.x, gb+2);
            PROC(f2.y, f2.z, f2.w, gb+3);
        }
    }

    // covariance of the 10-neighborhood (match reference: /10.0, plain ops)
    float px[KNN], py[KNN], pz[KNN];
    {
#pragma clang fp contract(off)
        float sx = 0.f, sy = 0.f, sz = 0.f;
        #pragma unroll
        for (int s = 0; s < KNN; ++s) {
            const float* p = cl + (size_t)bi[s]*3;
            px[s] = p[0]; py[s] = p[1]; pz[s] = p[2];
            sx = sx + px[s]; sy = sy + py[s]; sz = sz + pz[s];
        }
        float mx = sx / 10.0f, my = sy / 10.0f, mz = sz / 10.0f;
        float c00=0.f,c01=0.f,c02=0.f,c11=0.f,c12=0.f,c22=0.f;
        #pragma unroll
        for (int s = 0; s < KNN; ++s) {
            float dx = px[s]-mx, dy = py[s]-my, dz = pz[s]-mz;
            c00 = c00 + dx*dx; c01 = c01 + dx*dy; c02 = c02 + dx*dz;
            c11 = c11 + dy*dy; c12 = c12 + dy*dz; c22 = c22 + dz*dz;
        }
        c00 = c00/10.0f; c01 = c01/10.0f; c02 = c02/10.0f;
        c11 = c11/10.0f; c12 = c12/10.0f; c22 = c22/10.0f;

        float nv[3];
        eigh3_smallest(c00, c01, c02, c11, c12, c22, nv);
        float* o = Nrm + ((size_t)pair*NN + q)*3;
        o[0] = nv[0]; o[1] = nv[1]; o[2] = nv[2];
    }
}

// ---------------------------------------------------------------------------
// Kernel C: per-point 1 - cos, block partial sums
// ---------------------------------------------------------------------------
__global__ __launch_bounds__(256) void loss_kernel(
    const float* __restrict__ Nrm, float* __restrict__ partials)
{
    int tid = threadIdx.x;
    int i = blockIdx.x * 256 + tid;            // 0..BN-1
    const float* g = Nrm + (size_t)i*3;
    const float* p = Nrm + ((size_t)BN + i)*3;
    float gx=g[0], gy=g[1], gz=g[2];
    float hx=p[0], hy=p[1], hz=p[2];
    float dot = fmaf(gx,hx,fmaf(gy,hy,gz*hz));
    float ng  = sqrtf(fmaf(gx,gx,fmaf(gy,gy,gz*gz)));
    float nh  = sqrtf(fmaf(hx,hx,fmaf(hy,hy,hz*hz)));
    float den = fmaxf(ng*nh, 1e-8f);
    float v = 1.0f - dot/den;

    __shared__ float red[256];
    red[tid] = v;
    __syncthreads();
    for (int s = 128; s > 0; s >>= 1) {
        if (tid < s) red[tid] += red[tid+s];
        __syncthreads();
    }
    if (tid == 0) partials[blockIdx.x] = red[0];
}

__global__ __launch_bounds__(128) void final_kernel(
    const float* __restrict__ partials, float* __restrict__ out)
{
    __shared__ float red[128];
    int tid = threadIdx.x;
    red[tid] = partials[tid];                  // exactly 128 partials
    __syncthreads();
    for (int s = 64; s > 0; s >>= 1) {
        if (tid < s) red[tid] += red[tid+s];
        __syncthreads();
    }
    if (tid == 0) out[0] = red[0] * (1.0f/(float)BN);
}

// ---------------------------------------------------------------------------
extern "C" void kernel_launch(void* const* d_in, const int* in_sizes, int n_in,
                              void* d_out, int out_size, void* d_ws, size_t ws_size,
                              hipStream_t stream)
{
    (void)in_sizes; (void)n_in; (void)out_size; (void)ws_size;
    const float*    gt   = (const float*)d_in[0];
    const float*    pred = (const float*)d_in[1];
    const unsigned* idxw = (const unsigned*)d_in[2];
    float* out = (float*)d_out;

    float* P        = (float*)d_ws;                 // 2*BN*3 floats
    float* Nrm      = P   + (size_t)2*BN*3;         // 2*BN*3 floats
    float* partials = Nrm + (size_t)2*BN*3;         // 128 floats

    hipLaunchKernelGGL(prep_kernel,       dim3(2*BN/256), dim3(256), 0, stream,
                       gt, pred, idxw, P);
    hipLaunchKernelGGL(knn_normal_kernel, dim3(2*BN/256), dim3(256), 0, stream,
                       P, Nrm);
    hipLaunchKernelGGL(loss_kernel,       dim3(BN/256),   dim3(256), 0, stream,
                       Nrm, partials);
    hipLaunchKernelGGL(final_kernel,      dim3(1),        dim3(128), 0, stream,
                       partials, out);
}

// Round 3
// 754.461 us; speedup vs baseline: 1.6763x; 1.6763x over previous
//
#include <hip/hip_runtime.h>
#include <math.h>

#define BB   4
#define NN   8192
#define BN   (BB*NN)       // 32768 points per cloud-set
#define KNN  10
#define SEGS 4             // candidate segments per query (= waves per block)
#define SEGLEN (NN/SEGS)   // 2048
#define TILE 256
#define NTILES (SEGLEN/TILE)

#define SEPS    5.9604645e-8f        // slamch('E') = 2^-24
#define SEPS2   (SEPS*SEPS)
#define SSAFMIN 1.1754944e-38f

// ---------------------------------------------------------------------------
// Kernel A: build P4[2][B][N] = (x,y,z,0): cloud0 = gt, cloud1 = pred[idx12].
// Also zeroes the loss accumulator + arrival counter.
// ---------------------------------------------------------------------------
__global__ __launch_bounds__(256) void prep_kernel(
    const float* __restrict__ gt, const float* __restrict__ pred,
    const unsigned* __restrict__ idxw, float4* __restrict__ P4,
    float* __restrict__ accum, unsigned* __restrict__ counter)
{
    __shared__ int s_is32;
    int tid = threadIdx.x;
    if (tid == 0) s_is32 = 0;
    __syncthreads();
    if (idxw[2*tid + 1] != 0u) s_is32 = 1;   // int64 => all high words 0
    __syncthreads();
    bool is64 = (s_is32 == 0);

    if (blockIdx.x == 0 && tid == 0) { *accum = 0.0f; *counter = 0u; }

    int point = blockIdx.x * 256 + tid;        // 0 .. 2*BN-1
    int cloud = point >> 15;                   // BN = 2^15
    int r = point & (BN - 1);
    float x, y, z;
    if (cloud == 0) {
        x = gt[(size_t)r*3+0]; y = gt[(size_t)r*3+1]; z = gt[(size_t)r*3+2];
    } else {
        int b = r >> 13;                       // NN = 2^13
        unsigned idx = is64 ? idxw[2*(size_t)r] : idxw[r];
        const float* src = pred + ((size_t)b*NN + idx)*3;
        x = src[0]; y = src[1]; z = src[2];
    }
    P4[point] = make_float4(x, y, z, 0.0f);
}

// ---------------------------------------------------------------------------
// LAPACK ssyevd 3x3 path: ssytrd('L') + sorgtr + ssteqr('V'). Sign-faithful.
// (verified absmax 0.0 in round 2 — do not touch)
// ---------------------------------------------------------------------------
__device__ __forceinline__ float f_sign(float a, float b) {
    return copysignf(a, b);
}
__device__ __forceinline__ float slapy2(float x, float y) {
#pragma clang fp contract(off)
    float xa = fabsf(x), ya = fabsf(y);
    float w = fmaxf(xa, ya), z = fminf(xa, ya);
    if (z == 0.0f) return w;
    float t = z / w;
    return w * __fsqrt_rn(1.0f + t*t);
}
__device__ __forceinline__ void slartg_(float f, float g, float* cs, float* sn, float* r) {
#pragma clang fp contract(off)
    if (g == 0.0f)      { *cs = 1.0f; *sn = 0.0f; *r = f; }
    else if (f == 0.0f) { *cs = 0.0f; *sn = f_sign(1.0f, g); *r = fabsf(g); }
    else {
        float f1 = fabsf(f);
        float d = __fsqrt_rn(f*f + g*g);
        float p = 1.0f / d;
        *cs = f1 * p;
        *sn = g * f_sign(p, f);
        *r  = f_sign(d, f);
    }
}
__device__ void slaev2_(float a, float b, float c,
                        float* rt1, float* rt2, float* cs1, float* sn1) {
#pragma clang fp contract(off)
    float sm = a + c, df = a - c;
    float adf = fabsf(df);
    float tb = b + b;
    float ab = fabsf(tb);
    float acmx, acmn;
    if (fabsf(a) > fabsf(c)) { acmx = a; acmn = c; } else { acmx = c; acmn = a; }
    float rt;
    if (adf > ab)      { float t = ab/adf; rt = adf*__fsqrt_rn(1.0f + t*t); }
    else if (adf < ab) { float t = adf/ab; rt = ab*__fsqrt_rn(1.0f + t*t); }
    else               { rt = ab*__fsqrt_rn(2.0f); }
    int sgn1;
    if (sm < 0.0f)      { *rt1 = 0.5f*(sm - rt); sgn1 = -1;
                          *rt2 = (acmx / *rt1)*acmn - (b / *rt1)*b; }
    else if (sm > 0.0f) { *rt1 = 0.5f*(sm + rt); sgn1 = 1;
                          *rt2 = (acmx / *rt1)*acmn - (b / *rt1)*b; }
    else                { *rt1 = 0.5f*rt; *rt2 = -0.5f*rt; sgn1 = 1; }
    float cs; int sgn2;
    if (df >= 0.0f) { cs = df + rt; sgn2 = 1; } else { cs = df - rt; sgn2 = -1; }
    float acs = fabsf(cs);
    float c1, s1;
    if (acs > ab) { float ct = -tb/cs; s1 = 1.0f/__fsqrt_rn(1.0f + ct*ct); c1 = ct*s1; }
    else {
        if (ab == 0.0f) { c1 = 1.0f; s1 = 0.0f; }
        else { float tn = -cs/tb; c1 = 1.0f/__fsqrt_rn(1.0f + tn*tn); s1 = tn*c1; }
    }
    if (sgn1 == sgn2) { float tn = c1; c1 = -s1; s1 = tn; }
    *cs1 = c1; *sn1 = s1;
}

__device__ void eigh3_smallest(float c00, float c01, float c02,
                               float c11, float c12, float c22, float nv[3])
{
#pragma clang fp contract(off)
    // ---- ssytrd('L') ----
    float d[4], e[3], z[4][4];
    float tau1, v2 = 0.0f;
    float e1, d2, d3, e2;
    float alpha = c01, x = c02;
    if (x == 0.0f) {
        tau1 = 0.0f; e1 = alpha;
        d2 = c11; d3 = c22; e2 = c12;
    } else {
        float beta = -f_sign(slapy2(alpha, fabsf(x)), alpha);
        tau1 = (beta - alpha) / beta;
        v2 = x / (alpha - beta);
        e1 = beta;
        float w1 = tau1*(c11 + c12*v2);
        float w2 = tau1*(c12 + c22*v2);
        float al = -0.5f*tau1*(w1 + w2*v2);
        w1 = w1 + al;
        w2 = w2 + al*v2;
        d2 = (c11 - w1) - w1;
        e2 = (c12 - v2*w1) - w2;
        d3 = (c22 - v2*w2) - w2*v2;
    }
    d[1] = c00; d[2] = d2; d[3] = d3;
    e[1] = e1;  e[2] = e2;
    z[1][1] = 1.0f; z[1][2] = 0.0f; z[1][3] = 0.0f;
    z[2][1] = 0.0f; z[3][1] = 0.0f;
    z[2][2] = 1.0f - tau1;
    float mtv = -tau1*v2;
    z[2][3] = mtv; z[3][2] = mtv;
    z[3][3] = 1.0f + mtv*v2;

    // ---- ssteqr('V', 3) ----
    const int n = 3, nm1 = 2;
    int l1 = 1, jtot = 0;
    const int nmaxit = 90;
    float cw[3], sw[3];
    int guard = 0;
    while (guard++ < 64) {
        if (l1 > n) break;
        if (l1 > 1) e[l1-1] = 0.0f;
        int m = n;
        if (l1 <= nm1) {
            for (int mi = l1; mi <= nm1; ++mi) {
                float tst = fabsf(e[mi]);
                if (tst == 0.0f) { m = mi; break; }
                if (tst <= (__fsqrt_rn(fabsf(d[mi]))*__fsqrt_rn(fabsf(d[mi+1])))*SEPS) {
                    e[mi] = 0.0f; m = mi; break;
                }
            }
        }
        int l = l1;
        int lsv = l, lend = m, lendsv = lend;
        l1 = m + 1;
        if (lend == l) continue;
        if (fabsf(d[lend]) < fabsf(d[l])) { lend = lsv; l = lendsv; }

        if (lend > l) {
            // QL
            while (true) {
                int m_ = lend;
                if (l != lend) {
                    for (int mi = l; mi <= lend-1; ++mi) {
                        float em = e[mi];
                        float tst = em*em;
                        if (tst <= (SEPS2*fabsf(d[mi]))*fabsf(d[mi+1]) + SSAFMIN) { m_ = mi; break; }
                    }
                }
                if (m_ < lend) e[m_] = 0.0f;
                float p = d[l];
                if (m_ == l) {
                    d[l] = p; l = l + 1;
                    if (l <= lend) continue; else break;
                }
                if (m_ == l + 1) {
                    float rt1, rt2, cc, ss;
                    slaev2_(d[l], e[l], d[l+1], &rt1, &rt2, &cc, &ss);
                    for (int i = 1; i <= 3; ++i) {
                        float tmp = z[i][l+1];
                        z[i][l+1] = cc*tmp - ss*z[i][l];
                        z[i][l]   = ss*tmp + cc*z[i][l];
                    }
                    d[l] = rt1; d[l+1] = rt2; e[l] = 0.0f;
                    l = l + 2;
                    if (l <= lend) continue; else break;
                }
                if (jtot == nmaxit) break;
                jtot++;
                float g = (d[l+1] - p) / (2.0f*e[l]);
                float r = slapy2(g, 1.0f);
                g = d[m_] - p + (e[l] / (g + f_sign(r, g)));
                float s = 1.0f, c = 1.0f;
                p = 0.0f;
                for (int i = m_-1; i >= l; --i) {
                    float f = s*e[i];
                    float b = c*e[i];
                    slartg_(g, f, &c, &s, &r);
                    if (i != m_-1) e[i+1] = r;
                    g = d[i+1] - p;
                    r = (d[i] - g)*s + (2.0f*c)*b;
                    p = s*r;
                    d[i+1] = g + p;
                    g = c*r - b;
                    cw[i] = c; sw[i] = -s;
                }
                for (int j = m_-1; j >= l; --j) {
                    float cc = cw[j], ss = sw[j];
                    for (int i = 1; i <= 3; ++i) {
                        float tmp = z[i][j+1];
                        z[i][j+1] = cc*tmp - ss*z[i][j];
                        z[i][j]   = ss*tmp + cc*z[i][j];
                    }
                }
                d[l] = d[l] - p;
                e[l] = g;
            }
        } else {
            // QR
            while (true) {
                int m_ = lend;
                if (l != lend) {
                    for (int mi = l; mi >= lend+1; --mi) {
                        float em = e[mi-1];
                        float tst = em*em;
                        if (tst <= (SEPS2*fabsf(d[mi]))*fabsf(d[mi-1]) + SSAFMIN) { m_ = mi; break; }
                    }
                }
                if (m_ > lend) e[m_-1] = 0.0f;
                float p = d[l];
                if (m_ == l) {
                    d[l] = p; l = l - 1;
                    if (l >= lend) continue; else break;
                }
                if (m_ == l - 1) {
                    float rt1, rt2, cc, ss;
                    slaev2_(d[l-1], e[l-1], d[l], &rt1, &rt2, &cc, &ss);
                    for (int i = 1; i <= 3; ++i) {
                        float tmp = z[i][l];
                        z[i][l]   = cc*tmp - ss*z[i][l-1];
                        z[i][l-1] = ss*tmp + cc*z[i][l-1];
                    }
                    d[l-1] = rt1; d[l] = rt2; e[l-1] = 0.0f;
                    l = l - 2;
                    if (l >= lend) continue; else break;
                }
                if (jtot == nmaxit) break;
                jtot++;
                float g = (d[l-1] - p) / (2.0f*e[l-1]);
                float r = slapy2(g, 1.0f);
                g = d[m_] - p + (e[l-1] / (g + f_sign(r, g)));
                float s = 1.0f, c = 1.0f;
                p = 0.0f;
                for (int i = m_; i <= l-1; ++i) {
                    float f = s*e[i];
                    float b = c*e[i];
                    slartg_(g, f, &c, &s, &r);
                    if (i != m_) e[i-1] = r;
                    g = d[i] - p;
                    r = (d[i+1] - g)*s + (2.0f*c)*b;
                    p = s*r;
                    d[i] = g + p;
                    g = c*r - b;
                    cw[i] = c; sw[i] = s;
                }
                for (int j = m_; j <= l-1; ++j) {
                    float cc = cw[j], ss = sw[j];
                    for (int i = 1; i <= 3; ++i) {
                        float tmp = z[i][j+1];
                        z[i][j+1] = cc*tmp - ss*z[i][j];
                        z[i][j]   = ss*tmp + cc*z[i][j];
                    }
                }
                d[l] = d[l] - p;
                e[l-1] = g;
            }
        }
    }
    for (int ii = 2; ii <= 3; ++ii) {
        int i = ii - 1, k = i;
        float p = d[i];
        for (int j = ii; j <= 3; ++j) if (d[j] < p) { k = j; p = d[j]; }
        if (k != i) {
            d[k] = d[i]; d[i] = p;
            for (int r2 = 1; r2 <= 3; ++r2) {
                float t = z[r2][i]; z[r2][i] = z[r2][k]; z[r2][k] = t;
            }
        }
    }
    nv[0] = z[1][1]; nv[1] = z[2][1]; nv[2] = z[3][1];
}

// ---------------------------------------------------------------------------
// Strict-< top-10 insert. Candidates always arrive in increasing index order
// (within a segment, and segments merge in index order), so strict float
// compare alone reproduces top_k's lexicographic (d, idx) tie rule.
// ---------------------------------------------------------------------------
__device__ __forceinline__ void ins10(float (&bd)[KNN], int (&bi)[KNN],
                                      float d, int j)
{
    float cd = d; int ci = j;
    #pragma unroll
    for (int s = 0; s < KNN; ++s) {
        float od = bd[s]; int oi = bi[s];
        bool sw = od > cd;
        bd[s] = sw ? cd : od;
        bi[s] = sw ? ci : oi;
        cd    = sw ? od : cd;
        ci    = sw ? oi : ci;
    }
}

// ---------------------------------------------------------------------------
// Kernel B: block = 4 waves = 64 queries. Wave w scans candidate segment w
// (2048 candidates) keeping a per-lane top-10; lists merged in LDS by wave 0,
// then covariance + LAPACK-faithful eigh + normal write.
// Grid: 1024 blocks -> 4 blocks/CU, 16 waves/CU (~50% occupancy).
// ---------------------------------------------------------------------------
__global__ __launch_bounds__(256, 4) void knn_normal_kernel(
    const float4* __restrict__ P4, float* __restrict__ Nrm)
{
    __shared__ __align__(16) float4 stage[SEGS][TILE];   // 16 KB
    __shared__ float ld[SEGS][64][KNN];                  // 10 KB
    __shared__ int   li[SEGS][64][KNN];                  // 10 KB

    int tid  = threadIdx.x;
    int w    = tid >> 6;
    int lane = tid & 63;
    int blk  = blockIdx.x;
    int pair = blk >> 7;                   // 8 (cloud,batch) pairs
    int chunk = blk & 127;                 // 128 blocks per pair
    const float4* __restrict__ cl = P4 + (size_t)pair * NN;

    int q = chunk * 64 + lane;
    float4 qp = cl[q];
    float qx = qp.x, qy = qp.y, qz = qp.z;

    float bd[KNN]; int bi[KNN];
    #pragma unroll
    for (int s = 0; s < KNN; ++s) { bd[s] = 3.4e38f; bi[s] = 0; }
    float worst = 3.4e38f;

    int segbase = w * SEGLEN;
    for (int t = 0; t < NTILES; ++t) {
        __syncthreads();
        #pragma unroll
        for (int k = 0; k < TILE/64; ++k)
            stage[w][lane + k*64] = cl[segbase + t*TILE + lane + k*64];
        __syncthreads();
        int gb = segbase + t*TILE;
        #pragma unroll 2
        for (int j = 0; j < TILE; ++j) {
            float4 c = stage[w][j];
            float dx = qx - c.x, dy = qy - c.y, dz = qz - c.z;
            float dcur = fmaf(dz, dz, fmaf(dy, dy, dx*dx));
            if (dcur < worst) {
                ins10(bd, bi, dcur, gb + j);
                worst = bd[KNN-1];
            }
        }
    }

    #pragma unroll
    for (int s = 0; s < KNN; ++s) { ld[w][lane][s] = bd[s]; li[w][lane][s] = bi[s]; }
    __syncthreads();

    if (tid < 64) {
        float md[KNN]; int mi[KNN];
        #pragma unroll
        for (int s = 0; s < KNN; ++s) { md[s] = 3.4e38f; mi[s] = 0; }
        for (int w2 = 0; w2 < SEGS; ++w2) {
            #pragma unroll
            for (int s = 0; s < KNN; ++s) {
                float cd = ld[w2][tid][s];
                int   ci = li[w2][tid][s];
                if (cd < md[KNN-1]) ins10(md, mi, cd, ci);
            }
        }

        // covariance of the 10-neighborhood (order = sorted (d,idx) = ref order)
        {
#pragma clang fp contract(off)
            float px[KNN], py[KNN], pz[KNN];
            float sx = 0.f, sy = 0.f, sz = 0.f;
            #pragma unroll
            for (int s = 0; s < KNN; ++s) {
                float4 np = cl[mi[s]];
                px[s] = np.x; py[s] = np.y; pz[s] = np.z;
                sx = sx + px[s]; sy = sy + py[s]; sz = sz + pz[s];
            }
            float mx = sx / 10.0f, my = sy / 10.0f, mz = sz / 10.0f;
            float c00=0.f,c01=0.f,c02=0.f,c11=0.f,c12=0.f,c22=0.f;
            #pragma unroll
            for (int s = 0; s < KNN; ++s) {
                float dx = px[s]-mx, dy = py[s]-my, dz = pz[s]-mz;
                c00 = c00 + dx*dx; c01 = c01 + dx*dy; c02 = c02 + dx*dz;
                c11 = c11 + dy*dy; c12 = c12 + dy*dz; c22 = c22 + dz*dz;
            }
            c00 = c00/10.0f; c01 = c01/10.0f; c02 = c02/10.0f;
            c11 = c11/10.0f; c12 = c12/10.0f; c22 = c22/10.0f;

            float nv[3];
            eigh3_smallest(c00, c01, c02, c11, c12, c22, nv);
            float* o = Nrm + ((size_t)pair*NN + q)*3;
            o[0] = nv[0]; o[1] = nv[1]; o[2] = nv[2];
        }
    }
}

// ---------------------------------------------------------------------------
// Kernel C: per-point 1 - cos, block partial sums, device-scope atomic
// accumulate; last block writes the mean.
// ---------------------------------------------------------------------------
__global__ __launch_bounds__(256) void loss_final_kernel(
    const float* __restrict__ Nrm, float* __restrict__ accum,
    unsigned* __restrict__ counter, float* __restrict__ out)
{
    int tid = threadIdx.x;
    int i = blockIdx.x * 256 + tid;            // 0..BN-1
    const float* g = Nrm + (size_t)i*3;
    const float* p = Nrm + ((size_t)BN + i)*3;
    float gx=g[0], gy=g[1], gz=g[2];
    float hx=p[0], hy=p[1], hz=p[2];
    float dot = fmaf(gx,hx,fmaf(gy,hy,gz*hz));
    float ng  = sqrtf(fmaf(gx,gx,fmaf(gy,gy,gz*gz)));
    float nh  = sqrtf(fmaf(hx,hx,fmaf(hy,hy,hz*hz)));
    float den = fmaxf(ng*nh, 1e-8f);
    float v = 1.0f - dot/den;

    __shared__ float red[256];
    red[tid] = v;
    __syncthreads();
    for (int s = 128; s > 0; s >>= 1) {
        if (tid < s) red[tid] += red[tid+s];
        __syncthreads();
    }
    if (tid == 0) {
        atomicAdd(accum, red[0]);
        __threadfence();
        unsigned old = atomicAdd(counter, 1u);
        if (old == (unsigned)(BN/256 - 1)) {
            float tot = atomicAdd(accum, 0.0f);   // RMW read via L2 (coherent)
            out[0] = tot * (1.0f/(float)BN);
        }
    }
}

// ---------------------------------------------------------------------------
extern "C" void kernel_launch(void* const* d_in, const int* in_sizes, int n_in,
                              void* d_out, int out_size, void* d_ws, size_t ws_size,
                              hipStream_t stream)
{
    (void)in_sizes; (void)n_in; (void)out_size; (void)ws_size;
    const float*    gt   = (const float*)d_in[0];
    const float*    pred = (const float*)d_in[1];
    const unsigned* idxw = (const unsigned*)d_in[2];
    float* out = (float*)d_out;

    float4* P4       = (float4*)d_ws;                     // 2*BN float4 = 1 MB
    float*  Nrm      = (float*)(P4 + (size_t)2*BN);       // 2*BN*3 floats
    float*  accum    = Nrm + (size_t)2*BN*3;
    unsigned* counter = (unsigned*)(accum + 1);

    hipLaunchKernelGGL(prep_kernel,       dim3(2*BN/256), dim3(256), 0, stream,
                       gt, pred, idxw, P4, accum, counter);
    hipLaunchKernelGGL(knn_normal_kernel, dim3(2*BN/64),  dim3(256), 0, stream,
                       P4, Nrm);
    hipLaunchKernelGGL(loss_final_kernel, dim3(BN/256),   dim3(256), 0, stream,
                       Nrm, accum, counter, out);
}